// Round 2
// baseline (368.878 us; speedup 1.0000x reference)
//
#include <hip/hip_runtime.h>

// MMD loss, class-compacted, fused to 5 kernels + 1 small memset.
// total = concat(source[nsd:], target); N rows bucketed by class; only
// within-class pairwise distances are computed (everything outside the class
// masks is zero in the reference). Pass-A (m@D@m for bandwidth) uses the
// algebraic identity m@D@m = 2n*sum(sq) - 2*||sum x||^2 (clamp negligible,
// verified absmax 0.0 in round 1). Pair kernel exploits symmetry of
// sgn@K@sgn: only jt<=kt tiles, off-diagonal weighted 2x.

#define PAD 68  // LDS row stride in floats; compute reads are conflict-free

// ---- K1: per-row sq + label (argmax for target) + class counts + scan fold ----
__global__ __launch_bounds__(64) void k_prep(
    const float* __restrict__ src, const float* __restrict__ tgt,
    const int* __restrict__ slab, const float* __restrict__ tlabel,
    const int* __restrict__ nsd_p,
    int* __restrict__ lab, float* __restrict__ sq,
    int* cnt, int* srccnt, int* tgtcnt, int* done,
    int* offset, int* alloc, int* tprefix, int* misc,
    int S_total, int T, int D, int C) {
  int nsd = nsd_p[0];
  int S_use = S_total - nsd;
  int N = S_use + T;
  int r = blockIdx.x;
  int tid = threadIdx.x;
  if (r < N) {
    const float* row;
    int c;
    if (r < S_use) {
      row = src + (size_t)(nsd + r) * D;
      c = slab[nsd + r];
    } else {
      int t = r - S_use;
      row = tgt + (size_t)t * C * 0 + (size_t)t * D;  // tgt row
      row = tgt + (size_t)t * D;
      // argmax over C (first-max wins, matching jnp.argmax)
      float v = (tid < C) ? tlabel[(size_t)t * C + tid] : -3.4e38f;
      int idx = tid;
      for (int o = 32; o > 0; o >>= 1) {
        float ov = __shfl_down(v, o, 64);
        int oi = __shfl_down(idx, o, 64);
        if (ov > v || (ov == v && oi < idx)) { v = ov; idx = oi; }
      }
      c = __shfl(idx, 0, 64);
    }
    const float4* r4 = (const float4*)row;
    float s = 0.f;
    for (int i = tid; i < (D >> 2); i += 64) {
      float4 q = r4[i];
      s += q.x * q.x + q.y * q.y + q.z * q.z + q.w * q.w;
    }
    for (int o = 32; o > 0; o >>= 1) s += __shfl_down(s, o, 64);
    if (tid == 0) {
      sq[r] = s;
      lab[r] = c;
      atomicAdd(&cnt[c], 1);
      if (r < S_use) atomicAdd(&srccnt[c], 1); else atomicAdd(&tgtcnt[c], 1);
    }
  }
  // last-block fold: exclusive scan of counts + symmetric-tile prefix
  if (tid == 0) {
    __threadfence();
    int d = atomicAdd(&done[0], 1);
    if (d == (int)gridDim.x - 1) {
      int o = 0, tt = 0;
      for (int c2 = 0; c2 < C; c2++) {
        int n = atomicAdd(&cnt[c2], 0);  // device-coherent read (same kernel)
        offset[c2] = o; alloc[c2] = o; tprefix[c2] = tt;
        int tpr = (n + 31) >> 5;
        o += n;
        tt += tpr * (tpr + 1) / 2;  // upper-triangle tiles only
      }
      tprefix[C] = tt;
      misc[0] = tt;  // total tiles
      misc[1] = o;   // N
    }
  }
}

// ---- K2: assign compacted slot + gather row ----
__global__ __launch_bounds__(64) void k_gather(
    const float* __restrict__ src, const float* __restrict__ tgt,
    const int* __restrict__ nsd_p, const int* __restrict__ lab,
    const float* __restrict__ sq, int* alloc,
    float* __restrict__ compact, float* __restrict__ sqc, float* __restrict__ sgnc,
    int S_total, int T, int D) {
  int nsd = nsd_p[0];
  int S_use = S_total - nsd;
  int N = S_use + T;
  int r = blockIdx.x;
  if (r >= N) return;
  int tid = threadIdx.x;
  int pos;
  if (tid == 0) pos = atomicAdd(&alloc[lab[r]], 1);
  pos = __shfl(pos, 0, 64);
  const float* row = (r < S_use) ? src + (size_t)(nsd + r) * D
                                 : tgt + (size_t)(r - S_use) * D;
  const float4* s4 = (const float4*)row;
  float4* d4 = (float4*)(compact + (size_t)pos * D);
  for (int i = tid; i < (D >> 2); i += 64) d4[i] = s4[i];
  if (tid == 0) {
    sqc[pos] = sq[r];
    sgnc[pos] = (r < S_use) ? 1.f : -1.f;
  }
}

// ---- K3: per-class bandwidth via algebraic identity (one block per class) ----
__global__ __launch_bounds__(256) void k_stats(
    const float* __restrict__ compact, const float* __restrict__ sqc,
    const int* __restrict__ cnt, const int* __restrict__ offset,
    float* __restrict__ bwArr, int D) {
  int c = blockIdx.x;
  int tid = threadIdx.x;
  int n = cnt[c], off = offset[c];
  const float* base = compact + (size_t)off * D;
  int col0 = tid, col1 = tid + 256;
  float s0 = 0.f, s1 = 0.f;
  for (int i = 0; i < n; i++) {
    const float* rp = base + (size_t)i * D;
    if (col0 < D) s0 += rp[col0];
    if (col1 < D) s1 += rp[col1];
  }
  float acc = s0 * s0 + s1 * s1;  // contribution to ||sum x||^2
  float sv = 0.f;
  for (int i = tid; i < n; i += 256) sv += sqc[off + i];
  __shared__ float redA[4], redB[4];
  for (int o = 32; o > 0; o >>= 1) {
    acc += __shfl_down(acc, o, 64);
    sv  += __shfl_down(sv, o, 64);
  }
  if ((tid & 63) == 0) { redA[tid >> 6] = acc; redB[tid >> 6] = sv; }
  __syncthreads();
  if (tid == 0) {
    float ns = redA[0] + redA[1] + redA[2] + redA[3];
    float ss = redB[0] + redB[1] + redB[2] + redB[3];
    float nf = (float)n;
    float S1 = 2.f * nf * ss - 2.f * ns;  // == m @ Dmat @ m
    float bw = S1 / fmaxf(nf * nf - nf, 1.f);
    bw = (bw > 0.f) ? bw : 1.f;
    bwArr[c] = bw * 0.25f;  // / KERNEL_MUL^(KERNEL_NUM//2)
  }
}

// ---- K4: symmetric pair tiles (32x32, single-wave block, 4x4 micro) + final fold ----
__global__ __launch_bounds__(64) void k_pairs(
    const float* __restrict__ compact, const float* __restrict__ sqc,
    const float* __restrict__ sgnc, const int* __restrict__ cnt,
    const int* __restrict__ srccnt, const int* __restrict__ tgtcnt,
    const int* __restrict__ offset, const int* __restrict__ tprefix,
    const int* __restrict__ misc, const float* __restrict__ bwArr,
    float* losssum, int* done, float* __restrict__ out, int D, int C) {
  __shared__ float As[32 * PAD];
  __shared__ float Bs[32 * PAD];
  int tileTotal = misc[0];
  int tid = threadIdx.x;
  int ty = tid >> 3, tx = tid & 7;   // 8x8 thread grid, 4x4 micro-tile each
  for (int t = blockIdx.x; t < tileTotal; t += gridDim.x) {
    int c = 0;
    while (!(t >= tprefix[c] && t < tprefix[c + 1])) c++;
    int n = cnt[c], off = offset[c];
    int tpr = (n + 31) >> 5;
    int lt = t - tprefix[c];
    int jt = 0;
    while (lt >= tpr - jt) { lt -= tpr - jt; jt++; }
    int kt = jt + lt;                 // jt <= kt (upper triangle)
    int jbase = jt * 32, kbase = kt * 32;
    float w = (jt == kt) ? 1.f : 2.f;

    float acc[4][4];
    #pragma unroll
    for (int i = 0; i < 4; i++)
      #pragma unroll
      for (int j = 0; j < 4; j++) acc[i][j] = 0.f;

    for (int d0 = 0; d0 < D; d0 += 64) {
      // stage A (rows jbase..jbase+31) and B (rows kbase..) 64-float chunks
      #pragma unroll
      for (int it = 0; it < 8; it++) {
        int e = tid + 64 * it;
        int row = e >> 4;      // 0..31
        int c4 = e & 15;       // float4 index within 64-float chunk
        int jr = jbase + row, kr = kbase + row;
        float4 av = make_float4(0.f, 0.f, 0.f, 0.f);
        float4 bv = av;
        if (jr < n) av = *(const float4*)(compact + (size_t)(off + jr) * D + d0 + c4 * 4);
        if (kr < n) bv = *(const float4*)(compact + (size_t)(off + kr) * D + d0 + c4 * 4);
        *(float4*)(As + row * PAD + c4 * 4) = av;
        *(float4*)(Bs + row * PAD + c4 * 4) = bv;
      }
      __syncthreads();
      #pragma unroll
      for (int dq = 0; dq < 16; dq++) {
        float4 a[4], b[4];
        #pragma unroll
        for (int i = 0; i < 4; i++) {
          a[i] = *(const float4*)(As + (ty + 8 * i) * PAD + dq * 4);
          b[i] = *(const float4*)(Bs + (tx + 8 * i) * PAD + dq * 4);
        }
        #pragma unroll
        for (int i = 0; i < 4; i++)
          #pragma unroll
          for (int j = 0; j < 4; j++)
            acc[i][j] += a[i].x * b[j].x + a[i].y * b[j].y +
                         a[i].z * b[j].z + a[i].w * b[j].w;
      }
      __syncthreads();
    }

    float inv0 = 1.0f / bwArr[c];
    float contrib = 0.f;
    #pragma unroll
    for (int i = 0; i < 4; i++) {
      int j = jbase + ty + 8 * i;
      if (j >= n) continue;
      float sqj = sqc[off + j], sgj = sgnc[off + j];
      #pragma unroll
      for (int j2 = 0; j2 < 4; j2++) {
        int k = kbase + tx + 8 * j2;
        if (k >= n) continue;
        float d = fmaxf(sqj + sqc[off + k] - 2.f * acc[i][j2], 0.f);
        float s = inv0, kv = 0.f;
        #pragma unroll
        for (int q = 0; q < 5; q++) { kv += __expf(-d * s); s *= 0.5f; }
        contrib += sgj * sgnc[off + k] * kv;
      }
    }
    contrib *= w;
    for (int o = 32; o > 0; o >>= 1) contrib += __shfl_down(contrib, o, 64);
    if (tid == 0) atomicAdd(&losssum[c], contrib);
  }
  // final fold: last block computes the output scalar
  if (tid == 0) {
    __threadfence();
    int d = atomicAdd(&done[1], 1);
    if (d == (int)gridDim.x - 1) {
      float loss = 0.f, cv = 0.f;
      for (int c2 = 0; c2 < C; c2++) {
        if (srccnt[c2] > 0 && tgtcnt[c2] > 0) {
          float ls = atomicAdd(&losssum[c2], 0.f);  // same-kernel coherent read
          float nf = (float)cnt[c2];
          loss += ls / fmaxf(nf * nf, 1.f);
          cv += 1.f;
        }
      }
      out[0] = loss / fmaxf(cv, 1.f);
    }
  }
}

extern "C" void kernel_launch(void* const* d_in, const int* in_sizes, int n_in,
                              void* d_out, int out_size, void* d_ws, size_t ws_size,
                              hipStream_t stream) {
  const float* source = (const float*)d_in[0];
  const float* target = (const float*)d_in[1];
  const int* slab     = (const int*)d_in[2];
  const float* tlabel = (const float*)d_in[3];
  const int* nsd_p    = (const int*)d_in[4];
  float* out = (float*)d_out;

  int S_total = in_sizes[2];
  int D = in_sizes[0] / S_total;   // 512
  int T = in_sizes[1] / D;         // 2048
  int C = in_sizes[3] / T;         // 31
  int NMAX = S_total + T;          // 6144 upper bound; actual N read on device

  // workspace layout (4-byte words)
  float* ws = (float*)d_ws;
  int* cnt      = (int*)ws;             // C  -- zeroed
  int* srccnt   = cnt + C;              // C  -- zeroed
  int* tgtcnt   = srccnt + C;           // C  -- zeroed
  float* losssum = (float*)(tgtcnt + C);// C  -- zeroed
  int* done     = (int*)(losssum + C);  // 2  -- zeroed
  int* alloc    = done + 2;             // C
  int* offset   = alloc + C;            // C
  int* tprefix  = offset + C;           // C+1
  int* misc     = tprefix + C + 1;      // 2
  float* bwArr  = (float*)(misc + 2);   // C

  int* lab    = (int*)(ws + 1024);
  float* sq   = (float*)(lab + NMAX);
  float* sqc  = sq + NMAX;
  float* sgnc = sqc + NMAX;
  int words_used = 1024 + 4 * NMAX;
  int cw = (words_used + 63) & ~63;     // 256B-align compact
  float* compact = ws + cw;             // NMAX * D floats

  hipMemsetAsync(d_ws, 0, (size_t)(4 * C + 2) * sizeof(int), stream);

  k_prep<<<NMAX, 64, 0, stream>>>(source, target, slab, tlabel, nsd_p,
                                  lab, sq, cnt, srccnt, tgtcnt, done,
                                  offset, alloc, tprefix, misc,
                                  S_total, T, D, C);
  k_gather<<<NMAX, 64, 0, stream>>>(source, target, nsd_p, lab, sq, alloc,
                                    compact, sqc, sgnc, S_total, T, D);
  k_stats<<<C, 256, 0, stream>>>(compact, sqc, cnt, offset, bwArr, D);
  k_pairs<<<640, 64, 0, stream>>>(compact, sqc, sgnc, cnt, srccnt, tgtcnt,
                                  offset, tprefix, misc, bwArr,
                                  losssum, done, out, D, C);
}

// Round 3
// 238.472 us; speedup vs baseline: 1.5468x; 1.5468x over previous
//
#include <hip/hip_runtime.h>

// MMD loss, class-compacted. total = concat(source[nsd:], target); rows are
// bucketed by class and only within-class pairwise distances are computed.
// Bandwidth pass uses m@D@m = 2n*sum(sq) - 2*||sum x||^2 (clamp negligible;
// absmax 0.0 in rounds 1-2). Pair kernel: symmetric upper-triangle 32x32
// tiles, off-diagonal weighted 2x, single-wave blocks with 4x4 micro-tile.
//
// Round-3 fix: all device-scope fences / contended atomics now scale with
// GRID size (64 or 24 blocks), never with row count (6144). Round 2's 141us
// k_prep was 6144 x (__threadfence + same-address atomicAdd).

#define PAD 68   // LDS row stride in floats; compute reads conflict-free
#define CMAX 32  // >= CLASS_NUM (31)

// ---- K1: labels + row sq + class counts (LDS hist) + last-block scan ----
__global__ __launch_bounds__(256) void k_prep(
    const float* __restrict__ src, const float* __restrict__ tgt,
    const int* __restrict__ slab, const float* __restrict__ tlabel,
    const int* __restrict__ nsd_p,
    int* __restrict__ lab, float* __restrict__ sq,
    int* cnt, int* srccnt, int* tgtcnt, int* done,
    int* offset, int* alloc, int* tprefix, int* misc,
    int S_total, int T, int D, int C) {
  __shared__ int hcnt[CMAX], hsrc[CMAX], htgt[CMAX];
  int tid = threadIdx.x;
  if (tid < CMAX) { hcnt[tid] = 0; hsrc[tid] = 0; htgt[tid] = 0; }
  __syncthreads();

  int nsd = nsd_p[0];
  int S_use = S_total - nsd;
  int N = S_use + T;
  int lane = tid & 63;
  int wid = (blockIdx.x * 256 + tid) >> 6;
  int nw = (gridDim.x * 256) >> 6;

  for (int r = wid; r < N; r += nw) {
    int c;
    const float* row;
    if (r < S_use) {
      c = slab[nsd + r];
      row = src + (size_t)(nsd + r) * D;
    } else {
      int t = r - S_use;
      row = tgt + (size_t)t * D;
      // wave argmax over C (first-max wins, matching jnp.argmax)
      float v = (lane < C) ? tlabel[(size_t)t * C + lane] : -3.4e38f;
      int idx = lane;
      for (int o = 32; o > 0; o >>= 1) {
        float ov = __shfl_down(v, o, 64);
        int oi = __shfl_down(idx, o, 64);
        if (ov > v || (ov == v && oi < idx)) { v = ov; idx = oi; }
      }
      c = __shfl(idx, 0, 64);
    }
    const float4* r4 = (const float4*)row;
    float s = 0.f;
    for (int i = lane; i < (D >> 2); i += 64) {
      float4 q = r4[i];
      s += q.x * q.x + q.y * q.y + q.z * q.z + q.w * q.w;
    }
    for (int o = 32; o > 0; o >>= 1) s += __shfl_down(s, o, 64);
    if (lane == 0) {
      sq[r] = s;
      lab[r] = c;
      atomicAdd(&hcnt[c], 1);
      if (r < S_use) atomicAdd(&hsrc[c], 1); else atomicAdd(&htgt[c], 1);
    }
  }
  __syncthreads();
  if (tid < C) {
    if (hcnt[tid]) atomicAdd(&cnt[tid], hcnt[tid]);
    if (hsrc[tid]) atomicAdd(&srccnt[tid], hsrc[tid]);
    if (htgt[tid]) atomicAdd(&tgtcnt[tid], htgt[tid]);
  }
  __syncthreads();  // drain this block's global atomics before signaling done
  if (tid == 0) {
    __threadfence();
    int d = atomicAdd(&done[0], 1);
    if (d == (int)gridDim.x - 1) {
      int o = 0, tt = 0;
      for (int c2 = 0; c2 < C; c2++) {
        int n = atomicAdd(&cnt[c2], 0);  // device-coherent read
        offset[c2] = o; alloc[c2] = o; tprefix[c2] = tt;
        int tpr = (n + 31) >> 5;
        o += n;
        tt += tpr * (tpr + 1) / 2;  // upper-triangle tiles only
      }
      tprefix[C] = tt;
      misc[0] = tt;  // total tiles
      misc[1] = o;   // N
    }
  }
}

// ---- K2: compacted positions via two-level (LDS rank + per-block chunk) ----
__global__ __launch_bounds__(256) void k_pos(
    const int* __restrict__ lab, const float* __restrict__ sq,
    const int* __restrict__ nsd_p, int* alloc,
    int* __restrict__ posArr, float* __restrict__ sqc, float* __restrict__ sgnc,
    int S_total, int T, int C) {
  __shared__ int hist[CMAX], base[CMAX];
  int tid = threadIdx.x;
  if (tid < CMAX) hist[tid] = 0;
  __syncthreads();
  int nsd = nsd_p[0];
  int S_use = S_total - nsd;
  int N = S_use + T;
  int r = blockIdx.x * 256 + tid;
  int c = -1, l = 0;
  if (r < N) { c = lab[r]; l = atomicAdd(&hist[c], 1); }
  __syncthreads();
  if (tid < C && hist[tid] > 0) base[tid] = atomicAdd(&alloc[tid], hist[tid]);
  __syncthreads();
  if (r < N) {
    int p = base[c] + l;
    posArr[r] = p;
    sqc[p] = sq[r];
    sgnc[p] = (r < S_use) ? 1.f : -1.f;
  }
}

// ---- K3: gather rows into class-compacted layout (fence/atomic-free) ----
__global__ __launch_bounds__(64) void k_gather(
    const float* __restrict__ src, const float* __restrict__ tgt,
    const int* __restrict__ nsd_p, const int* __restrict__ posArr,
    float* __restrict__ compact, int S_total, int T, int D) {
  int nsd = nsd_p[0];
  int S_use = S_total - nsd;
  int N = S_use + T;
  int r = blockIdx.x;
  if (r >= N) return;
  int p = posArr[r];
  const float* row = (r < S_use) ? src + (size_t)(nsd + r) * D
                                 : tgt + (size_t)(r - S_use) * D;
  const float4* s4 = (const float4*)row;
  float4* d4 = (float4*)(compact + (size_t)p * D);
  for (int i = threadIdx.x; i < (D >> 2); i += 64) d4[i] = s4[i];
}

// ---- K4: per-class bandwidth via algebraic identity (one block/class) ----
__global__ __launch_bounds__(256) void k_stats(
    const float* __restrict__ compact, const float* __restrict__ sqc,
    const int* __restrict__ cnt, const int* __restrict__ offset,
    float* __restrict__ bwArr, int D) {
  int c = blockIdx.x;
  int tid = threadIdx.x;
  int n = cnt[c], off = offset[c];
  const float* base = compact + (size_t)off * D;
  int col0 = tid, col1 = tid + 256;
  float s0 = 0.f, s1 = 0.f;
  for (int i = 0; i < n; i++) {
    const float* rp = base + (size_t)i * D;
    if (col0 < D) s0 += rp[col0];
    if (col1 < D) s1 += rp[col1];
  }
  float acc = s0 * s0 + s1 * s1;  // -> ||sum x||^2
  float sv = 0.f;
  for (int i = tid; i < n; i += 256) sv += sqc[off + i];
  __shared__ float redA[4], redB[4];
  for (int o = 32; o > 0; o >>= 1) {
    acc += __shfl_down(acc, o, 64);
    sv  += __shfl_down(sv, o, 64);
  }
  if ((tid & 63) == 0) { redA[tid >> 6] = acc; redB[tid >> 6] = sv; }
  __syncthreads();
  if (tid == 0) {
    float ns = redA[0] + redA[1] + redA[2] + redA[3];
    float ss = redB[0] + redB[1] + redB[2] + redB[3];
    float nf = (float)n;
    float S1 = 2.f * nf * ss - 2.f * ns;  // == m @ Dmat @ m
    float bw = S1 / fmaxf(nf * nf - nf, 1.f);
    bw = (bw > 0.f) ? bw : 1.f;
    bwArr[c] = bw * 0.25f;  // / KERNEL_MUL^(KERNEL_NUM//2)
  }
}

// ---- K5: symmetric pair tiles (32x32, 1-wave blocks, 4x4 micro) ----
__global__ __launch_bounds__(64) void k_pairs(
    const float* __restrict__ compact, const float* __restrict__ sqc,
    const float* __restrict__ sgnc, const int* __restrict__ cnt,
    const int* __restrict__ offset, const int* __restrict__ tprefix,
    const int* __restrict__ misc, const float* __restrict__ bwArr,
    float* losssum, int D, int C) {
  __shared__ float As[32 * PAD];
  __shared__ float Bs[32 * PAD];
  int tileTotal = misc[0];
  int tid = threadIdx.x;
  int ty = tid >> 3, tx = tid & 7;   // 8x8 thread grid, 4x4 micro-tile
  for (int t = blockIdx.x; t < tileTotal; t += gridDim.x) {
    int c = 0;
    while (!(t >= tprefix[c] && t < tprefix[c + 1])) c++;
    int n = cnt[c], off = offset[c];
    int tpr = (n + 31) >> 5;
    int lt = t - tprefix[c];
    int jt = 0;
    while (lt >= tpr - jt) { lt -= tpr - jt; jt++; }
    int kt = jt + lt;                 // jt <= kt
    int jbase = jt * 32, kbase = kt * 32;
    float w = (jt == kt) ? 1.f : 2.f;

    float acc[4][4];
    #pragma unroll
    for (int i = 0; i < 4; i++)
      #pragma unroll
      for (int j = 0; j < 4; j++) acc[i][j] = 0.f;

    for (int d0 = 0; d0 < D; d0 += 64) {
      #pragma unroll
      for (int it = 0; it < 8; it++) {
        int e = tid + 64 * it;
        int row = e >> 4, c4 = e & 15;
        int jr = jbase + row, kr = kbase + row;
        float4 av = make_float4(0.f, 0.f, 0.f, 0.f);
        float4 bv = av;
        if (jr < n) av = *(const float4*)(compact + (size_t)(off + jr) * D + d0 + c4 * 4);
        if (kr < n) bv = *(const float4*)(compact + (size_t)(off + kr) * D + d0 + c4 * 4);
        *(float4*)(As + row * PAD + c4 * 4) = av;
        *(float4*)(Bs + row * PAD + c4 * 4) = bv;
      }
      __syncthreads();
      #pragma unroll
      for (int dq = 0; dq < 16; dq++) {
        float4 a[4], b[4];
        #pragma unroll
        for (int i = 0; i < 4; i++) {
          a[i] = *(const float4*)(As + (ty + 8 * i) * PAD + dq * 4);
          b[i] = *(const float4*)(Bs + (tx + 8 * i) * PAD + dq * 4);
        }
        #pragma unroll
        for (int i = 0; i < 4; i++)
          #pragma unroll
          for (int j = 0; j < 4; j++)
            acc[i][j] += a[i].x * b[j].x + a[i].y * b[j].y +
                         a[i].z * b[j].z + a[i].w * b[j].w;
      }
      __syncthreads();
    }

    float inv0 = 1.0f / bwArr[c];
    float contrib = 0.f;
    #pragma unroll
    for (int i = 0; i < 4; i++) {
      int j = jbase + ty + 8 * i;
      if (j >= n) continue;
      float sqj = sqc[off + j], sgj = sgnc[off + j];
      #pragma unroll
      for (int j2 = 0; j2 < 4; j2++) {
        int k = kbase + tx + 8 * j2;
        if (k >= n) continue;
        float d = fmaxf(sqj + sqc[off + k] - 2.f * acc[i][j2], 0.f);
        float s = inv0, kv = 0.f;
        #pragma unroll
        for (int q = 0; q < 5; q++) { kv += __expf(-d * s); s *= 0.5f; }
        contrib += sgj * sgnc[off + k] * kv;
      }
    }
    contrib *= w;
    for (int o = 32; o > 0; o >>= 1) contrib += __shfl_down(contrib, o, 64);
    if (tid == 0) atomicAdd(&losssum[c], contrib);
  }
}

// ---- K6: final scalar ----
__global__ void k_final(const int* __restrict__ cnt, const int* __restrict__ srccnt,
                        const int* __restrict__ tgtcnt, const float* __restrict__ losssum,
                        float* out, int C) {
  if (threadIdx.x != 0 || blockIdx.x != 0) return;
  float loss = 0.f, cv = 0.f;
  for (int c = 0; c < C; c++) {
    if (srccnt[c] > 0 && tgtcnt[c] > 0) {
      float nf = (float)cnt[c];
      loss += losssum[c] / fmaxf(nf * nf, 1.f);
      cv += 1.f;
    }
  }
  out[0] = loss / fmaxf(cv, 1.f);
}

extern "C" void kernel_launch(void* const* d_in, const int* in_sizes, int n_in,
                              void* d_out, int out_size, void* d_ws, size_t ws_size,
                              hipStream_t stream) {
  const float* source = (const float*)d_in[0];
  const float* target = (const float*)d_in[1];
  const int* slab     = (const int*)d_in[2];
  const float* tlabel = (const float*)d_in[3];
  const int* nsd_p    = (const int*)d_in[4];
  float* out = (float*)d_out;

  int S_total = in_sizes[2];
  int D = in_sizes[0] / S_total;   // 512
  int T = in_sizes[1] / D;         // 2048
  int C = in_sizes[3] / T;         // 31
  int NMAX = S_total + T;          // 6144 upper bound; actual N read on device

  // workspace layout (4-byte words)
  float* ws = (float*)d_ws;
  int* cnt      = (int*)ws;             // C  -- zeroed
  int* srccnt   = cnt + C;              // C  -- zeroed
  int* tgtcnt   = srccnt + C;           // C  -- zeroed
  float* losssum = (float*)(tgtcnt + C);// C  -- zeroed
  int* done     = (int*)(losssum + C);  // 2  -- zeroed
  int* alloc    = done + 2;             // C
  int* offset   = alloc + C;            // C
  int* tprefix  = offset + C;           // C+1
  int* misc     = tprefix + C + 1;      // 2
  float* bwArr  = (float*)(misc + 2);   // C

  int* lab     = (int*)(ws + 1024);     // NMAX
  float* sq    = (float*)(lab + NMAX);  // NMAX
  float* sqc   = sq + NMAX;             // NMAX
  float* sgnc  = sqc + NMAX;            // NMAX
  int* posArr  = (int*)(sgnc + NMAX);   // NMAX
  int words_used = 1024 + 5 * NMAX;
  int cw = (words_used + 63) & ~63;     // 256B-align compact
  float* compact = ws + cw;             // NMAX * D floats

  hipMemsetAsync(d_ws, 0, (size_t)(4 * C + 2) * sizeof(int), stream);

  k_prep<<<64, 256, 0, stream>>>(source, target, slab, tlabel, nsd_p,
                                 lab, sq, cnt, srccnt, tgtcnt, done,
                                 offset, alloc, tprefix, misc,
                                 S_total, T, D, C);
  k_pos<<<(NMAX + 255) / 256, 256, 0, stream>>>(lab, sq, nsd_p, alloc,
                                                posArr, sqc, sgnc, S_total, T, C);
  k_gather<<<NMAX, 64, 0, stream>>>(source, target, nsd_p, posArr,
                                    compact, S_total, T, D);
  k_stats<<<C, 256, 0, stream>>>(compact, sqc, cnt, offset, bwArr, D);
  k_pairs<<<512, 64, 0, stream>>>(compact, sqc, sgnc, cnt, offset, tprefix,
                                  misc, bwArr, losssum, D, C);
  k_final<<<1, 64, 0, stream>>>(cnt, srccnt, tgtcnt, losssum, out, C);
}

// Round 4
// 171.149 us; speedup vs baseline: 2.1553x; 1.3934x over previous
//
#include <hip/hip_runtime.h>

// MMD loss, class-compacted. total = concat(source[nsd:], target); rows are
// bucketed by class; only within-class pairwise distances are computed.
// Bandwidth pass uses m@D@m = 2n*sum(sq) - 2*||sum x||^2 (absmax 0.0, r1-r3).
// Pair kernel: symmetric upper-triangle 32x32 tiles, off-diag weighted 2x.
//
// r4 fix: k_stats (78us, 31 blocks, latency-bound serial row walk) split into
// k_colsum (C x 8 row-chunk blocks, atomicAdd partials) + tiny k_bw.
// k_final parallelized (was 1 thread x ~124 dependent L2 reads).

#define PAD 68   // LDS row stride in floats; compute reads conflict-free
#define CMAX 32  // >= CLASS_NUM (31)
#define RCHUNK 8 // row-chunk parallelism for k_colsum

// ---- K1: labels + row sq + class counts (LDS hist) + last-block scan ----
__global__ __launch_bounds__(256) void k_prep(
    const float* __restrict__ src, const float* __restrict__ tgt,
    const int* __restrict__ slab, const float* __restrict__ tlabel,
    const int* __restrict__ nsd_p,
    int* __restrict__ lab, float* __restrict__ sq,
    int* cnt, int* srccnt, int* tgtcnt, int* done,
    int* offset, int* alloc, int* tprefix, int* misc,
    int S_total, int T, int D, int C) {
  __shared__ int hcnt[CMAX], hsrc[CMAX], htgt[CMAX];
  int tid = threadIdx.x;
  if (tid < CMAX) { hcnt[tid] = 0; hsrc[tid] = 0; htgt[tid] = 0; }
  __syncthreads();

  int nsd = nsd_p[0];
  int S_use = S_total - nsd;
  int N = S_use + T;
  int lane = tid & 63;
  int wid = (blockIdx.x * 256 + tid) >> 6;
  int nw = (gridDim.x * 256) >> 6;

  for (int r = wid; r < N; r += nw) {
    int c;
    const float* row;
    if (r < S_use) {
      c = slab[nsd + r];
      row = src + (size_t)(nsd + r) * D;
    } else {
      int t = r - S_use;
      row = tgt + (size_t)t * D;
      // wave argmax over C (first-max wins, matching jnp.argmax)
      float v = (lane < C) ? tlabel[(size_t)t * C + lane] : -3.4e38f;
      int idx = lane;
      for (int o = 32; o > 0; o >>= 1) {
        float ov = __shfl_down(v, o, 64);
        int oi = __shfl_down(idx, o, 64);
        if (ov > v || (ov == v && oi < idx)) { v = ov; idx = oi; }
      }
      c = __shfl(idx, 0, 64);
    }
    const float4* r4 = (const float4*)row;
    float s = 0.f;
    for (int i = lane; i < (D >> 2); i += 64) {
      float4 q = r4[i];
      s += q.x * q.x + q.y * q.y + q.z * q.z + q.w * q.w;
    }
    for (int o = 32; o > 0; o >>= 1) s += __shfl_down(s, o, 64);
    if (lane == 0) {
      sq[r] = s;
      lab[r] = c;
      atomicAdd(&hcnt[c], 1);
      if (r < S_use) atomicAdd(&hsrc[c], 1); else atomicAdd(&htgt[c], 1);
    }
  }
  __syncthreads();
  if (tid < C) {
    if (hcnt[tid]) atomicAdd(&cnt[tid], hcnt[tid]);
    if (hsrc[tid]) atomicAdd(&srccnt[tid], hsrc[tid]);
    if (htgt[tid]) atomicAdd(&tgtcnt[tid], htgt[tid]);
  }
  __syncthreads();  // drain this block's global atomics before signaling done
  if (tid == 0) {
    __threadfence();
    int d = atomicAdd(&done[0], 1);
    if (d == (int)gridDim.x - 1) {
      int o = 0, tt = 0;
      for (int c2 = 0; c2 < C; c2++) {
        int n = atomicAdd(&cnt[c2], 0);  // device-coherent read
        offset[c2] = o; alloc[c2] = o; tprefix[c2] = tt;
        int tpr = (n + 31) >> 5;
        o += n;
        tt += tpr * (tpr + 1) / 2;  // upper-triangle tiles only
      }
      tprefix[C] = tt;
      misc[0] = tt;  // total tiles
      misc[1] = o;   // N
    }
  }
}

// ---- K2: compacted positions via two-level (LDS rank + per-block chunk) ----
__global__ __launch_bounds__(256) void k_pos(
    const int* __restrict__ lab, const float* __restrict__ sq,
    const int* __restrict__ nsd_p, int* alloc,
    int* __restrict__ posArr, float* __restrict__ sqc, float* __restrict__ sgnc,
    int S_total, int T, int C) {
  __shared__ int hist[CMAX], base[CMAX];
  int tid = threadIdx.x;
  if (tid < CMAX) hist[tid] = 0;
  __syncthreads();
  int nsd = nsd_p[0];
  int S_use = S_total - nsd;
  int N = S_use + T;
  int r = blockIdx.x * 256 + tid;
  int c = -1, l = 0;
  if (r < N) { c = lab[r]; l = atomicAdd(&hist[c], 1); }
  __syncthreads();
  if (tid < C && hist[tid] > 0) base[tid] = atomicAdd(&alloc[tid], hist[tid]);
  __syncthreads();
  if (r < N) {
    int p = base[c] + l;
    posArr[r] = p;
    sqc[p] = sq[r];
    sgnc[p] = (r < S_use) ? 1.f : -1.f;
  }
}

// ---- K3: gather rows into class-compacted layout (fence/atomic-free) ----
__global__ __launch_bounds__(64) void k_gather(
    const float* __restrict__ src, const float* __restrict__ tgt,
    const int* __restrict__ nsd_p, const int* __restrict__ posArr,
    float* __restrict__ compact, int S_total, int T, int D) {
  int nsd = nsd_p[0];
  int S_use = S_total - nsd;
  int N = S_use + T;
  int r = blockIdx.x;
  if (r >= N) return;
  int p = posArr[r];
  const float* row = (r < S_use) ? src + (size_t)(nsd + r) * D
                                 : tgt + (size_t)(r - S_use) * D;
  const float4* s4 = (const float4*)row;
  float4* d4 = (float4*)(compact + (size_t)p * D);
  for (int i = threadIdx.x; i < (D >> 2); i += 64) d4[i] = s4[i];
}

// ---- K4: per-class column-sum partials (row-chunk parallel) ----
__global__ __launch_bounds__(256) void k_colsum(
    const float* __restrict__ compact, const int* __restrict__ cnt,
    const int* __restrict__ offset, float* __restrict__ colsum, int D) {
  int c = blockIdx.x;
  int n = cnt[c], off = offset[c];
  int i0 = (int)(((long long)n * blockIdx.y) / gridDim.y);
  int i1 = (int)(((long long)n * (blockIdx.y + 1)) / gridDim.y);
  int tid = threadIdx.x;
  const float* base = compact + (size_t)off * D;
  for (int col = tid; col < D; col += 256) {
    float s = 0.f;
    for (int i = i0; i < i1; i++) s += base[(size_t)i * D + col];
    if (s != 0.f) atomicAdd(&colsum[(size_t)c * D + col], s);
  }
}

// ---- K5: per-class bandwidth from colsum + sqc ----
__global__ __launch_bounds__(256) void k_bw(
    const float* __restrict__ colsum, const float* __restrict__ sqc,
    const int* __restrict__ cnt, const int* __restrict__ offset,
    float* __restrict__ bwArr, int D) {
  int c = blockIdx.x;
  int tid = threadIdx.x;
  int n = cnt[c], off = offset[c];
  float acc = 0.f;
  for (int d = tid; d < D; d += 256) {
    float v = colsum[(size_t)c * D + d];
    acc += v * v;
  }
  float sv = 0.f;
  for (int i = tid; i < n; i += 256) sv += sqc[off + i];
  __shared__ float redA[4], redB[4];
  for (int o = 32; o > 0; o >>= 1) {
    acc += __shfl_down(acc, o, 64);
    sv  += __shfl_down(sv, o, 64);
  }
  if ((tid & 63) == 0) { redA[tid >> 6] = acc; redB[tid >> 6] = sv; }
  __syncthreads();
  if (tid == 0) {
    float ns = redA[0] + redA[1] + redA[2] + redA[3];  // ||sum x||^2
    float ss = redB[0] + redB[1] + redB[2] + redB[3];  // sum sq
    float nf = (float)n;
    float S1 = 2.f * nf * ss - 2.f * ns;  // == m @ Dmat @ m
    float bw = S1 / fmaxf(nf * nf - nf, 1.f);
    bw = (bw > 0.f) ? bw : 1.f;
    bwArr[c] = bw * 0.25f;  // / KERNEL_MUL^(KERNEL_NUM//2)
  }
}

// ---- K6: symmetric pair tiles (32x32, 1-wave blocks, 4x4 micro) ----
__global__ __launch_bounds__(64) void k_pairs(
    const float* __restrict__ compact, const float* __restrict__ sqc,
    const float* __restrict__ sgnc, const int* __restrict__ cnt,
    const int* __restrict__ offset, const int* __restrict__ tprefix,
    const int* __restrict__ misc, const float* __restrict__ bwArr,
    float* losssum, int D, int C) {
  __shared__ float As[32 * PAD];
  __shared__ float Bs[32 * PAD];
  int tileTotal = misc[0];
  int tid = threadIdx.x;
  int ty = tid >> 3, tx = tid & 7;   // 8x8 thread grid, 4x4 micro-tile
  for (int t = blockIdx.x; t < tileTotal; t += gridDim.x) {
    int c = 0;
    while (!(t >= tprefix[c] && t < tprefix[c + 1])) c++;
    int n = cnt[c], off = offset[c];
    int tpr = (n + 31) >> 5;
    int lt = t - tprefix[c];
    int jt = 0;
    while (lt >= tpr - jt) { lt -= tpr - jt; jt++; }
    int kt = jt + lt;                 // jt <= kt
    int jbase = jt * 32, kbase = kt * 32;
    float w = (jt == kt) ? 1.f : 2.f;

    float acc[4][4];
    #pragma unroll
    for (int i = 0; i < 4; i++)
      #pragma unroll
      for (int j = 0; j < 4; j++) acc[i][j] = 0.f;

    for (int d0 = 0; d0 < D; d0 += 64) {
      #pragma unroll
      for (int it = 0; it < 8; it++) {
        int e = tid + 64 * it;
        int row = e >> 4, c4 = e & 15;
        int jr = jbase + row, kr = kbase + row;
        float4 av = make_float4(0.f, 0.f, 0.f, 0.f);
        float4 bv = av;
        if (jr < n) av = *(const float4*)(compact + (size_t)(off + jr) * D + d0 + c4 * 4);
        if (kr < n) bv = *(const float4*)(compact + (size_t)(off + kr) * D + d0 + c4 * 4);
        *(float4*)(As + row * PAD + c4 * 4) = av;
        *(float4*)(Bs + row * PAD + c4 * 4) = bv;
      }
      __syncthreads();
      #pragma unroll
      for (int dq = 0; dq < 16; dq++) {
        float4 a[4], b[4];
        #pragma unroll
        for (int i = 0; i < 4; i++) {
          a[i] = *(const float4*)(As + (ty + 8 * i) * PAD + dq * 4);
          b[i] = *(const float4*)(Bs + (tx + 8 * i) * PAD + dq * 4);
        }
        #pragma unroll
        for (int i = 0; i < 4; i++)
          #pragma unroll
          for (int j = 0; j < 4; j++)
            acc[i][j] += a[i].x * b[j].x + a[i].y * b[j].y +
                         a[i].z * b[j].z + a[i].w * b[j].w;
      }
      __syncthreads();
    }

    float inv0 = 1.0f / bwArr[c];
    float contrib = 0.f;
    #pragma unroll
    for (int i = 0; i < 4; i++) {
      int j = jbase + ty + 8 * i;
      if (j >= n) continue;
      float sqj = sqc[off + j], sgj = sgnc[off + j];
      #pragma unroll
      for (int j2 = 0; j2 < 4; j2++) {
        int k = kbase + tx + 8 * j2;
        if (k >= n) continue;
        float d = fmaxf(sqj + sqc[off + k] - 2.f * acc[i][j2], 0.f);
        float s = inv0, kv = 0.f;
        #pragma unroll
        for (int q = 0; q < 5; q++) { kv += __expf(-d * s); s *= 0.5f; }
        contrib += sgj * sgnc[off + k] * kv;
      }
    }
    contrib *= w;
    for (int o = 32; o > 0; o >>= 1) contrib += __shfl_down(contrib, o, 64);
    if (tid == 0) atomicAdd(&losssum[c], contrib);
  }
}

// ---- K7: final scalar (lane-per-class, parallel) ----
__global__ __launch_bounds__(64) void k_final(
    const int* __restrict__ cnt, const int* __restrict__ srccnt,
    const int* __restrict__ tgtcnt, const float* __restrict__ losssum,
    float* out, int C) {
  int c = threadIdx.x;
  float loss = 0.f, cv = 0.f;
  if (c < C && srccnt[c] > 0 && tgtcnt[c] > 0) {
    float nf = (float)cnt[c];
    loss = losssum[c] / fmaxf(nf * nf, 1.f);
    cv = 1.f;
  }
  for (int o = 32; o > 0; o >>= 1) {
    loss += __shfl_down(loss, o, 64);
    cv   += __shfl_down(cv, o, 64);
  }
  if (threadIdx.x == 0) out[0] = loss / fmaxf(cv, 1.f);
}

extern "C" void kernel_launch(void* const* d_in, const int* in_sizes, int n_in,
                              void* d_out, int out_size, void* d_ws, size_t ws_size,
                              hipStream_t stream) {
  const float* source = (const float*)d_in[0];
  const float* target = (const float*)d_in[1];
  const int* slab     = (const int*)d_in[2];
  const float* tlabel = (const float*)d_in[3];
  const int* nsd_p    = (const int*)d_in[4];
  float* out = (float*)d_out;

  int S_total = in_sizes[2];
  int D = in_sizes[0] / S_total;   // 512
  int T = in_sizes[1] / D;         // 2048
  int C = in_sizes[3] / T;         // 31
  int NMAX = S_total + T;          // 6144 upper bound; actual N read on device

  // workspace layout (4-byte words); zeroed region first
  float* ws = (float*)d_ws;
  int* cnt      = (int*)ws;              // C
  int* srccnt   = cnt + C;               // C
  int* tgtcnt   = srccnt + C;            // C
  float* losssum = (float*)(tgtcnt + C); // C
  int* done     = (int*)(losssum + C);   // 2
  float* colsum = (float*)(done + 2);    // C*D
  int zwords    = 4 * C + 2 + C * D;     // all zeroed

  int* alloc    = (int*)(colsum + (size_t)C * D);  // C
  int* offset   = alloc + C;             // C
  int* tprefix  = offset + C;            // C+1
  int* misc     = tprefix + C + 1;       // 2
  float* bwArr  = (float*)(misc + 2);    // C
  int* lab      = (int*)(bwArr + C);     // NMAX
  float* sq     = (float*)(lab + NMAX);  // NMAX
  float* sqc    = sq + NMAX;             // NMAX
  float* sgnc   = sqc + NMAX;            // NMAX
  int* posArr   = (int*)(sgnc + NMAX);   // NMAX
  int words_used = zwords + (4 * C + 3) + 5 * NMAX;
  int cw = (words_used + 63) & ~63;      // 256B-align compact
  float* compact = ws + cw;              // NMAX * D floats

  hipMemsetAsync(d_ws, 0, (size_t)zwords * sizeof(int), stream);

  k_prep<<<64, 256, 0, stream>>>(source, target, slab, tlabel, nsd_p,
                                 lab, sq, cnt, srccnt, tgtcnt, done,
                                 offset, alloc, tprefix, misc,
                                 S_total, T, D, C);
  k_pos<<<(NMAX + 255) / 256, 256, 0, stream>>>(lab, sq, nsd_p, alloc,
                                                posArr, sqc, sgnc, S_total, T, C);
  k_gather<<<NMAX, 64, 0, stream>>>(source, target, nsd_p, posArr,
                                    compact, S_total, T, D);
  k_colsum<<<dim3(C, RCHUNK), 256, 0, stream>>>(compact, cnt, offset, colsum, D);
  k_bw<<<C, 256, 0, stream>>>(colsum, sqc, cnt, offset, bwArr, D);
  k_pairs<<<512, 64, 0, stream>>>(compact, sqc, sgnc, cnt, offset, tprefix,
                                  misc, bwArr, losssum, D, C);
  k_final<<<1, 64, 0, stream>>>(cnt, srccnt, tgtcnt, losssum, out, C);
}

// Round 5
// 156.744 us; speedup vs baseline: 2.3534x; 1.0919x over previous
//
#include <hip/hip_runtime.h>

// MMD loss, class-compacted. total = concat(source[nsd:], target); rows are
// bucketed by class; only within-class pairwise distances computed.
// Bandwidth: m@D@m = 2n*sum(sq) - 2*||sum x||^2 (absmax 0.0, r1-r4).
// r5: k_pairs re-built as 4-wave blocks (D-split + reg double-buffer) to fix
// MLP starvation (was 2 waves/CU, 283 GB/s, VALUBusy 8%). colsum folded into
// k_prep via spread fp atomics; scan+bw fused; tile table precomputed.

#define PAD 68    // LDS row stride (floats); compute reads conflict-free
#define CMAX 32   // >= CLASS_NUM (31)
#define TCAP 12288

// ---- K1: labels + row sq + class counts + ssum + colsum (spread atomics) ----
__global__ __launch_bounds__(256) void k_prep(
    const float* __restrict__ src, const float* __restrict__ tgt,
    const int* __restrict__ slab, const float* __restrict__ tlabel,
    const int* __restrict__ nsd_p,
    int* __restrict__ lab, float* __restrict__ sq,
    int* cnt, int* srccnt, int* tgtcnt, float* ssum, float* colsum,
    int S_total, int T, int D, int C) {
  int nsd = nsd_p[0];
  int S_use = S_total - nsd;
  int N = S_use + T;
  int lane = threadIdx.x & 63;
  int wid = (blockIdx.x * blockDim.x + threadIdx.x) >> 6;
  int nw = (gridDim.x * blockDim.x) >> 6;
  for (int r = wid; r < N; r += nw) {
    int c;
    const float* row;
    if (r < S_use) {
      c = slab[nsd + r];
      row = src + (size_t)(nsd + r) * D;
    } else {
      int t = r - S_use;
      row = tgt + (size_t)t * D;
      float v = (lane < C) ? tlabel[(size_t)t * C + lane] : -3.4e38f;
      int idx = lane;
      for (int o = 32; o > 0; o >>= 1) {
        float ov = __shfl_down(v, o, 64);
        int oi = __shfl_down(idx, o, 64);
        if (ov > v || (ov == v && oi < idx)) { v = ov; idx = oi; }
      }
      c = __shfl(idx, 0, 64);
    }
    const float4* r4 = (const float4*)row;
    float* cb = colsum + (size_t)c * D;
    float s = 0.f;
    for (int i = lane; i < (D >> 2); i += 64) {
      float4 q = r4[i];
      s += q.x * q.x + q.y * q.y + q.z * q.z + q.w * q.w;
      atomicAdd(cb + i * 4 + 0, q.x);
      atomicAdd(cb + i * 4 + 1, q.y);
      atomicAdd(cb + i * 4 + 2, q.z);
      atomicAdd(cb + i * 4 + 3, q.w);
    }
    for (int o = 32; o > 0; o >>= 1) s += __shfl_down(s, o, 64);
    if (lane == 0) {
      sq[r] = s; lab[r] = c;
      atomicAdd(&cnt[c], 1);
      atomicAdd(&ssum[c], s);
      if (r < S_use) atomicAdd(&srccnt[c], 1); else atomicAdd(&tgtcnt[c], 1);
    }
  }
}

// ---- K2: block0 = scan + tile table; blocks 1..C = per-class bandwidth ----
__global__ __launch_bounds__(256) void k_scan_bw(
    const int* __restrict__ cnt, const float* __restrict__ ssum,
    const float* __restrict__ colsum,
    int* offset, int* alloc, int* misc,
    int* tileinfo, int* tileinfo2, float* bwArr, int C, int D) {
  __shared__ int s_tp[CMAX + 1], s_tpr[CMAX], s_off[CMAX], s_n[CMAX];
  __shared__ float red[4];
  int tid = threadIdx.x;
  if (blockIdx.x == 0) {
    if (tid == 0) {
      int o = 0, tt = 0;
      for (int c = 0; c < C; c++) {
        int n = cnt[c];
        s_off[c] = o; s_n[c] = n;
        offset[c] = o; alloc[c] = o;
        int tpr = (n + 31) >> 5;
        s_tpr[c] = tpr; s_tp[c] = tt;
        o += n; tt += tpr * (tpr + 1) / 2;
      }
      s_tp[C] = tt;
      misc[0] = tt; misc[1] = o;
    }
    __syncthreads();
    int tt = s_tp[C];
    for (int t = tid; t < tt; t += 256) {
      int c = 0;
      while (t >= s_tp[c + 1]) c++;
      int lt = t - s_tp[c];
      int tpr = s_tpr[c];
      int jt = 0;
      while (lt >= tpr - jt) { lt -= tpr - jt; jt++; }
      int kt = jt + lt;
      tileinfo[t] = c | (jt << 8) | (kt << 16);
      tileinfo2[t] = s_off[c] | (s_n[c] << 16);
    }
  } else {
    int c = blockIdx.x - 1;
    if (c >= C) return;
    float acc = 0.f;
    for (int d = tid; d < D; d += 256) {
      float v = colsum[(size_t)c * D + d];
      acc += v * v;
    }
    for (int o = 32; o > 0; o >>= 1) acc += __shfl_down(acc, o, 64);
    if ((tid & 63) == 0) red[tid >> 6] = acc;
    __syncthreads();
    if (tid == 0) {
      float ns = red[0] + red[1] + red[2] + red[3];  // ||sum x||^2
      float nf = (float)cnt[c];
      float S1 = 2.f * nf * ssum[c] - 2.f * ns;      // == m @ Dmat @ m
      float bw = S1 / fmaxf(nf * nf - nf, 1.f);
      bw = (bw > 0.f) ? bw : 1.f;
      bwArr[c] = bw * 0.25f;  // / KERNEL_MUL^(KERNEL_NUM//2)
    }
  }
}

// ---- K3: compacted positions (two-level: LDS rank + per-block chunk) ----
__global__ __launch_bounds__(256) void k_pos(
    const int* __restrict__ lab, const float* __restrict__ sq,
    const int* __restrict__ nsd_p, int* alloc,
    int* __restrict__ posArr, float* __restrict__ sqc, float* __restrict__ sgnc,
    int S_total, int T, int C) {
  __shared__ int hist[CMAX], base[CMAX];
  int tid = threadIdx.x;
  if (tid < CMAX) hist[tid] = 0;
  __syncthreads();
  int nsd = nsd_p[0];
  int S_use = S_total - nsd;
  int N = S_use + T;
  int r = blockIdx.x * 256 + tid;
  int c = -1, l = 0;
  if (r < N) { c = lab[r]; l = atomicAdd(&hist[c], 1); }
  __syncthreads();
  if (tid < C && hist[tid] > 0) base[tid] = atomicAdd(&alloc[tid], hist[tid]);
  __syncthreads();
  if (r < N) {
    int p = base[c] + l;
    posArr[r] = p;
    sqc[p] = sq[r];
    sgnc[p] = (r < S_use) ? 1.f : -1.f;
  }
}

// ---- K4: gather rows into class-compacted layout ----
__global__ __launch_bounds__(64) void k_gather(
    const float* __restrict__ src, const float* __restrict__ tgt,
    const int* __restrict__ nsd_p, const int* __restrict__ posArr,
    float* __restrict__ compact, int S_total, int T, int D) {
  int nsd = nsd_p[0];
  int S_use = S_total - nsd;
  int N = S_use + T;
  int r = blockIdx.x;
  if (r >= N) return;
  int p = posArr[r];
  const float* row = (r < S_use) ? src + (size_t)(nsd + r) * D
                                 : tgt + (size_t)(r - S_use) * D;
  const float4* s4 = (const float4*)row;
  float4* d4 = (float4*)(compact + (size_t)p * D);
  for (int i = threadIdx.x; i < (D >> 2); i += 64) d4[i] = s4[i];
}

// ---- K5: pair tiles. 32x32 tile per 256-thr block; 4 waves split the dq
// dimension; register double-buffered staging; LDS cross-wave dot reduce. ----
__global__ __launch_bounds__(256) void k_pairs(
    const float* __restrict__ compact, const float* __restrict__ sqc,
    const float* __restrict__ sgnc, const int* __restrict__ tileinfo,
    const int* __restrict__ tileinfo2, const int* __restrict__ misc,
    const float* __restrict__ bwArr, float* losssum, int D) {
  __shared__ float As[32 * PAD];
  __shared__ float Bs[32 * PAD];
  __shared__ float tileacc[32 * 37];
  __shared__ float red[4];
  int tileTotal = misc[0];
  int tid = threadIdx.x;
  int w = tid >> 6;            // wave 0..3 -> dq range
  int lane = tid & 63;
  int ty = lane >> 3, tx = lane & 7;
  int row0 = tid >> 4;         // 0..15 (staging row, +16 for second half)
  int c40 = tid & 15;          // float4 column within 64-float chunk
  int nch = D >> 6;            // 64-float chunks

  for (int t = blockIdx.x; t < tileTotal; t += gridDim.x) {
    int info = tileinfo[t];
    int c = info & 255, jt = (info >> 8) & 255, kt = (info >> 16) & 255;
    int info2 = tileinfo2[t];
    int off = info2 & 0xFFFF;
    int n = ((unsigned)info2) >> 16;
    int jbase = jt << 5, kbase = kt << 5;
    float wgt = (jt == kt) ? 1.f : 2.f;
    const float* base = compact + (size_t)off * D;

    int jr0 = jbase + row0, jr1 = jbase + 16 + row0;
    int kr0 = kbase + row0, kr1 = kbase + 16 + row0;
    const float4 z4 = make_float4(0.f, 0.f, 0.f, 0.f);
    float4 pa0, pa1, pb0, pb1;
    {
      const float* p = base + c40 * 4;
      pa0 = (jr0 < n) ? *(const float4*)(p + (size_t)jr0 * D) : z4;
      pa1 = (jr1 < n) ? *(const float4*)(p + (size_t)jr1 * D) : z4;
      pb0 = (kr0 < n) ? *(const float4*)(p + (size_t)kr0 * D) : z4;
      pb1 = (kr1 < n) ? *(const float4*)(p + (size_t)kr1 * D) : z4;
    }
    float acc[4][4];
    #pragma unroll
    for (int i = 0; i < 4; i++)
      #pragma unroll
      for (int j = 0; j < 4; j++) acc[i][j] = 0.f;

    for (int ch = 0; ch < nch; ch++) {
      *(float4*)(As + row0 * PAD + c40 * 4) = pa0;
      *(float4*)(As + (16 + row0) * PAD + c40 * 4) = pa1;
      *(float4*)(Bs + row0 * PAD + c40 * 4) = pb0;
      *(float4*)(Bs + (16 + row0) * PAD + c40 * 4) = pb1;
      __syncthreads();
      if (ch + 1 < nch) {   // prefetch next chunk; latency hidden by compute
        const float* p = base + (ch + 1) * 64 + c40 * 4;
        pa0 = (jr0 < n) ? *(const float4*)(p + (size_t)jr0 * D) : z4;
        pa1 = (jr1 < n) ? *(const float4*)(p + (size_t)jr1 * D) : z4;
        pb0 = (kr0 < n) ? *(const float4*)(p + (size_t)kr0 * D) : z4;
        pb1 = (kr1 < n) ? *(const float4*)(p + (size_t)kr1 * D) : z4;
      }
      #pragma unroll
      for (int dqi = 0; dqi < 4; dqi++) {
        int dq = (w << 2) + dqi;     // this wave's dq quarter
        float4 a[4], b[4];
        #pragma unroll
        for (int i = 0; i < 4; i++) {
          a[i] = *(const float4*)(As + (ty + 8 * i) * PAD + dq * 4);
          b[i] = *(const float4*)(Bs + (tx + 8 * i) * PAD + dq * 4);
        }
        #pragma unroll
        for (int i = 0; i < 4; i++)
          #pragma unroll
          for (int j = 0; j < 4; j++)
            acc[i][j] += a[i].x * b[j].x + a[i].y * b[j].y +
                         a[i].z * b[j].z + a[i].w * b[j].w;
      }
      __syncthreads();
    }

    // cross-wave reduction of partial dots into tileacc
    for (int ph = 0; ph < 4; ph++) {
      if (w == ph) {
        #pragma unroll
        for (int i = 0; i < 4; i++)
          #pragma unroll
          for (int j = 0; j < 4; j++) {
            int idx = (ty + 8 * i) * 37 + (tx + 8 * j);
            if (ph == 0) tileacc[idx] = acc[i][j];
            else tileacc[idx] += acc[i][j];
          }
      }
      __syncthreads();
    }

    // epilogue: 4 pairs per thread
    float inv0 = 1.f / bwArr[c];
    float contrib = 0.f;
    #pragma unroll
    for (int pi = 0; pi < 4; pi++) {
      int p = tid + (pi << 8);
      int j = p >> 5, k = p & 31;
      if (jbase + j < n && kbase + k < n) {
        float dot = tileacc[j * 37 + k];
        float d = fmaxf(sqc[off + jbase + j] + sqc[off + kbase + k] - 2.f * dot, 0.f);
        float s = inv0, kv = 0.f;
        #pragma unroll
        for (int q = 0; q < 5; q++) { kv += __expf(-d * s); s *= 0.5f; }
        contrib += sgnc[off + jbase + j] * sgnc[off + kbase + k] * kv;
      }
    }
    contrib *= wgt;
    for (int o = 32; o > 0; o >>= 1) contrib += __shfl_down(contrib, o, 64);
    if (lane == 0) red[w] = contrib;
    __syncthreads();
    if (tid == 0) atomicAdd(&losssum[c], red[0] + red[1] + red[2] + red[3]);
  }
}

// ---- K6: final scalar ----
__global__ __launch_bounds__(64) void k_final(
    const int* __restrict__ cnt, const int* __restrict__ srccnt,
    const int* __restrict__ tgtcnt, const float* __restrict__ losssum,
    float* out, int C) {
  int c = threadIdx.x;
  float loss = 0.f, cv = 0.f;
  if (c < C && srccnt[c] > 0 && tgtcnt[c] > 0) {
    float nf = (float)cnt[c];
    loss = losssum[c] / fmaxf(nf * nf, 1.f);
    cv = 1.f;
  }
  for (int o = 32; o > 0; o >>= 1) {
    loss += __shfl_down(loss, o, 64);
    cv   += __shfl_down(cv, o, 64);
  }
  if (threadIdx.x == 0) out[0] = loss / fmaxf(cv, 1.f);
}

extern "C" void kernel_launch(void* const* d_in, const int* in_sizes, int n_in,
                              void* d_out, int out_size, void* d_ws, size_t ws_size,
                              hipStream_t stream) {
  const float* source = (const float*)d_in[0];
  const float* target = (const float*)d_in[1];
  const int* slab     = (const int*)d_in[2];
  const float* tlabel = (const float*)d_in[3];
  const int* nsd_p    = (const int*)d_in[4];
  float* out = (float*)d_out;

  int S_total = in_sizes[2];
  int D = in_sizes[0] / S_total;   // 512
  int T = in_sizes[1] / D;         // 2048
  int C = in_sizes[3] / T;         // 31
  int NMAX = S_total + T;          // 6144 upper bound; actual N read on device

  // workspace layout (4-byte words); zeroed region first
  float* ws = (float*)d_ws;
  int* cnt      = (int*)ws;               // C
  int* srccnt   = cnt + C;                // C
  int* tgtcnt   = srccnt + C;             // C
  float* losssum = (float*)(tgtcnt + C);  // C
  float* ssum   = losssum + C;            // C
  float* colsum = ssum + C;               // C*D
  int zwords    = 5 * C + C * D;          // all zeroed

  int* offset   = (int*)(colsum + (size_t)C * D);  // C
  int* alloc    = offset + C;             // C
  int* misc     = alloc + C;              // 2
  float* bwArr  = (float*)(misc + 2);     // C
  int* lab      = (int*)(bwArr + C);      // NMAX
  float* sq     = (float*)(lab + NMAX);   // NMAX
  float* sqc    = sq + NMAX;              // NMAX
  float* sgnc   = sqc + NMAX;             // NMAX
  int* posArr   = (int*)(sgnc + NMAX);    // NMAX
  int* tileinfo = posArr + NMAX;          // TCAP
  int* tileinfo2 = tileinfo + TCAP;       // TCAP
  size_t words_used = (size_t)zwords + (3 * C + 2) + 5 * NMAX + 2 * TCAP;
  size_t cw = (words_used + 63) & ~(size_t)63;   // 256B-align compact
  float* compact = ws + cw;               // NMAX * D floats

  hipMemsetAsync(d_ws, 0, (size_t)zwords * sizeof(int), stream);

  k_prep<<<768, 256, 0, stream>>>(source, target, slab, tlabel, nsd_p,
                                  lab, sq, cnt, srccnt, tgtcnt, ssum, colsum,
                                  S_total, T, D, C);
  k_scan_bw<<<C + 1, 256, 0, stream>>>(cnt, ssum, colsum, offset, alloc, misc,
                                       tileinfo, tileinfo2, bwArr, C, D);
  k_pos<<<(NMAX + 255) / 256, 256, 0, stream>>>(lab, sq, nsd_p, alloc,
                                                posArr, sqc, sgnc, S_total, T, C);
  k_gather<<<NMAX, 64, 0, stream>>>(source, target, nsd_p, posArr,
                                    compact, S_total, T, D);
  k_pairs<<<512, 256, 0, stream>>>(compact, sqc, sgnc, tileinfo, tileinfo2,
                                   misc, bwArr, losssum, D);
  k_final<<<1, 64, 0, stream>>>(cnt, srccnt, tgtcnt, losssum, out, C);
}

// Round 6
// 148.051 us; speedup vs baseline: 2.4916x; 1.0587x over previous
//
#include <hip/hip_runtime.h>

// MMD loss, class-compacted. total = concat(source[nsd:], target); rows are
// bucketed by class; only within-class pairwise distances computed.
// Bandwidth: m@D@m = 2n*sum(sq) - 2*||sum x||^2 (absmax 0.0, r1-r5).
// r6: revert r5's colsum-in-prep (2.1M global fp atomics -> 34MB HBM writes,
// 55us). colsum is its own kernel on the compacted layout (496 blocks, 254K
// spread atomics). k_pairs kept verbatim from r5 (4-wave blocks, D-split,
// register double-buffer, tile table).

#define PAD 68    // LDS row stride (floats); compute reads conflict-free
#define CMAX 32   // >= CLASS_NUM (31)
#define TCAP 12288
#define RCHUNK 16 // row-chunk parallelism for k_colsum

// ---- K1: labels + row sq + class counts + ssum ----
__global__ __launch_bounds__(256) void k_prep(
    const float* __restrict__ src, const float* __restrict__ tgt,
    const int* __restrict__ slab, const float* __restrict__ tlabel,
    const int* __restrict__ nsd_p,
    int* __restrict__ lab, float* __restrict__ sq,
    int* cnt, int* srccnt, int* tgtcnt, float* ssum,
    int S_total, int T, int D, int C) {
  int nsd = nsd_p[0];
  int S_use = S_total - nsd;
  int N = S_use + T;
  int lane = threadIdx.x & 63;
  int wid = (blockIdx.x * blockDim.x + threadIdx.x) >> 6;
  int nw = (gridDim.x * blockDim.x) >> 6;
  for (int r = wid; r < N; r += nw) {
    int c;
    const float* row;
    if (r < S_use) {
      c = slab[nsd + r];
      row = src + (size_t)(nsd + r) * D;
    } else {
      int t = r - S_use;
      row = tgt + (size_t)t * D;
      float v = (lane < C) ? tlabel[(size_t)t * C + lane] : -3.4e38f;
      int idx = lane;
      for (int o = 32; o > 0; o >>= 1) {
        float ov = __shfl_down(v, o, 64);
        int oi = __shfl_down(idx, o, 64);
        if (ov > v || (ov == v && oi < idx)) { v = ov; idx = oi; }
      }
      c = __shfl(idx, 0, 64);
    }
    const float4* r4 = (const float4*)row;
    float s = 0.f;
    for (int i = lane; i < (D >> 2); i += 64) {
      float4 q = r4[i];
      s += q.x * q.x + q.y * q.y + q.z * q.z + q.w * q.w;
    }
    for (int o = 32; o > 0; o >>= 1) s += __shfl_down(s, o, 64);
    if (lane == 0) {
      sq[r] = s; lab[r] = c;
      atomicAdd(&cnt[c], 1);
      atomicAdd(&ssum[c], s);
      if (r < S_use) atomicAdd(&srccnt[c], 1); else atomicAdd(&tgtcnt[c], 1);
    }
  }
}

// ---- K2: scan of counts + per-tile lookup table (single block) ----
__global__ __launch_bounds__(256) void k_scan(
    const int* __restrict__ cnt, int* offset, int* alloc, int* misc,
    int* tileinfo, int* tileinfo2, int C) {
  __shared__ int s_tp[CMAX + 1], s_tpr[CMAX], s_off[CMAX], s_n[CMAX];
  int tid = threadIdx.x;
  if (tid == 0) {
    int o = 0, tt = 0;
    for (int c = 0; c < C; c++) {
      int n = cnt[c];
      s_off[c] = o; s_n[c] = n;
      offset[c] = o; alloc[c] = o;
      int tpr = (n + 31) >> 5;
      s_tpr[c] = tpr; s_tp[c] = tt;
      o += n; tt += tpr * (tpr + 1) / 2;
    }
    s_tp[C] = tt;
    misc[0] = tt; misc[1] = o;
  }
  __syncthreads();
  int tt = s_tp[C];
  for (int t = tid; t < tt; t += 256) {
    int c = 0;
    while (t >= s_tp[c + 1]) c++;
    int lt = t - s_tp[c];
    int tpr = s_tpr[c];
    int jt = 0;
    while (lt >= tpr - jt) { lt -= tpr - jt; jt++; }
    int kt = jt + lt;
    tileinfo[t] = c | (jt << 8) | (kt << 16);
    tileinfo2[t] = s_off[c] | (s_n[c] << 16);
  }
}

// ---- K3: compacted positions (two-level: LDS rank + per-block chunk) ----
__global__ __launch_bounds__(256) void k_pos(
    const int* __restrict__ lab, const float* __restrict__ sq,
    const int* __restrict__ nsd_p, int* alloc,
    int* __restrict__ posArr, float* __restrict__ sqc, float* __restrict__ sgnc,
    int S_total, int T, int C) {
  __shared__ int hist[CMAX], base[CMAX];
  int tid = threadIdx.x;
  if (tid < CMAX) hist[tid] = 0;
  __syncthreads();
  int nsd = nsd_p[0];
  int S_use = S_total - nsd;
  int N = S_use + T;
  int r = blockIdx.x * 256 + tid;
  int c = -1, l = 0;
  if (r < N) { c = lab[r]; l = atomicAdd(&hist[c], 1); }
  __syncthreads();
  if (tid < C && hist[tid] > 0) base[tid] = atomicAdd(&alloc[tid], hist[tid]);
  __syncthreads();
  if (r < N) {
    int p = base[c] + l;
    posArr[r] = p;
    sqc[p] = sq[r];
    sgnc[p] = (r < S_use) ? 1.f : -1.f;
  }
}

// ---- K4: gather rows into class-compacted layout ----
__global__ __launch_bounds__(64) void k_gather(
    const float* __restrict__ src, const float* __restrict__ tgt,
    const int* __restrict__ nsd_p, const int* __restrict__ posArr,
    float* __restrict__ compact, int S_total, int T, int D) {
  int nsd = nsd_p[0];
  int S_use = S_total - nsd;
  int N = S_use + T;
  int r = blockIdx.x;
  if (r >= N) return;
  int p = posArr[r];
  const float* row = (r < S_use) ? src + (size_t)(nsd + r) * D
                                 : tgt + (size_t)(r - S_use) * D;
  const float4* s4 = (const float4*)row;
  float4* d4 = (float4*)(compact + (size_t)p * D);
  for (int i = threadIdx.x; i < (D >> 2); i += 64) d4[i] = s4[i];
}

// ---- K5: per-class column-sum partials (row-chunk parallel, compacted) ----
__global__ __launch_bounds__(256) void k_colsum(
    const float* __restrict__ compact, const int* __restrict__ cnt,
    const int* __restrict__ offset, float* __restrict__ colsum, int D) {
  int c = blockIdx.x;
  int n = cnt[c], off = offset[c];
  int i0 = (int)(((long long)n * blockIdx.y) / gridDim.y);
  int i1 = (int)(((long long)n * (blockIdx.y + 1)) / gridDim.y);
  int tid = threadIdx.x;
  const float* base = compact + (size_t)off * D;
  for (int col = tid; col < D; col += 256) {
    float s = 0.f;
    for (int i = i0; i < i1; i++) s += base[(size_t)i * D + col];
    if (s != 0.f) atomicAdd(&colsum[(size_t)c * D + col], s);
  }
}

// ---- K6: per-class bandwidth from colsum + ssum ----
__global__ __launch_bounds__(256) void k_bw(
    const float* __restrict__ colsum, const float* __restrict__ ssum,
    const int* __restrict__ cnt, float* __restrict__ bwArr, int D) {
  __shared__ float red[4];
  int c = blockIdx.x;
  int tid = threadIdx.x;
  float acc = 0.f;
  for (int d = tid; d < D; d += 256) {
    float v = colsum[(size_t)c * D + d];
    acc += v * v;
  }
  for (int o = 32; o > 0; o >>= 1) acc += __shfl_down(acc, o, 64);
  if ((tid & 63) == 0) red[tid >> 6] = acc;
  __syncthreads();
  if (tid == 0) {
    float ns = red[0] + red[1] + red[2] + red[3];  // ||sum x||^2
    float nf = (float)cnt[c];
    float S1 = 2.f * nf * ssum[c] - 2.f * ns;      // == m @ Dmat @ m
    float bw = S1 / fmaxf(nf * nf - nf, 1.f);
    bw = (bw > 0.f) ? bw : 1.f;
    bwArr[c] = bw * 0.25f;  // / KERNEL_MUL^(KERNEL_NUM//2)
  }
}

// ---- K7: pair tiles. 32x32 tile per 256-thr block; 4 waves split the dq
// dimension; register double-buffered staging; LDS cross-wave dot reduce. ----
__global__ __launch_bounds__(256) void k_pairs(
    const float* __restrict__ compact, const float* __restrict__ sqc,
    const float* __restrict__ sgnc, const int* __restrict__ tileinfo,
    const int* __restrict__ tileinfo2, const int* __restrict__ misc,
    const float* __restrict__ bwArr, float* losssum, int D) {
  __shared__ float As[32 * PAD];
  __shared__ float Bs[32 * PAD];
  __shared__ float tileacc[32 * 37];
  __shared__ float red[4];
  int tileTotal = misc[0];
  int tid = threadIdx.x;
  int w = tid >> 6;            // wave 0..3 -> dq range
  int lane = tid & 63;
  int ty = lane >> 3, tx = lane & 7;
  int row0 = tid >> 4;         // 0..15 (staging row, +16 for second half)
  int c40 = tid & 15;          // float4 column within 64-float chunk
  int nch = D >> 6;            // 64-float chunks

  for (int t = blockIdx.x; t < tileTotal; t += gridDim.x) {
    int info = tileinfo[t];
    int c = info & 255, jt = (info >> 8) & 255, kt = (info >> 16) & 255;
    int info2 = tileinfo2[t];
    int off = info2 & 0xFFFF;
    int n = ((unsigned)info2) >> 16;
    int jbase = jt << 5, kbase = kt << 5;
    float wgt = (jt == kt) ? 1.f : 2.f;
    const float* base = compact + (size_t)off * D;

    int jr0 = jbase + row0, jr1 = jbase + 16 + row0;
    int kr0 = kbase + row0, kr1 = kbase + 16 + row0;
    const float4 z4 = make_float4(0.f, 0.f, 0.f, 0.f);
    float4 pa0, pa1, pb0, pb1;
    {
      const float* p = base + c40 * 4;
      pa0 = (jr0 < n) ? *(const float4*)(p + (size_t)jr0 * D) : z4;
      pa1 = (jr1 < n) ? *(const float4*)(p + (size_t)jr1 * D) : z4;
      pb0 = (kr0 < n) ? *(const float4*)(p + (size_t)kr0 * D) : z4;
      pb1 = (kr1 < n) ? *(const float4*)(p + (size_t)kr1 * D) : z4;
    }
    float acc[4][4];
    #pragma unroll
    for (int i = 0; i < 4; i++)
      #pragma unroll
      for (int j = 0; j < 4; j++) acc[i][j] = 0.f;

    for (int ch = 0; ch < nch; ch++) {
      *(float4*)(As + row0 * PAD + c40 * 4) = pa0;
      *(float4*)(As + (16 + row0) * PAD + c40 * 4) = pa1;
      *(float4*)(Bs + row0 * PAD + c40 * 4) = pb0;
      *(float4*)(Bs + (16 + row0) * PAD + c40 * 4) = pb1;
      __syncthreads();
      if (ch + 1 < nch) {   // prefetch next chunk; latency hidden by compute
        const float* p = base + (ch + 1) * 64 + c40 * 4;
        pa0 = (jr0 < n) ? *(const float4*)(p + (size_t)jr0 * D) : z4;
        pa1 = (jr1 < n) ? *(const float4*)(p + (size_t)jr1 * D) : z4;
        pb0 = (kr0 < n) ? *(const float4*)(p + (size_t)kr0 * D) : z4;
        pb1 = (kr1 < n) ? *(const float4*)(p + (size_t)kr1 * D) : z4;
      }
      #pragma unroll
      for (int dqi = 0; dqi < 4; dqi++) {
        int dq = (w << 2) + dqi;     // this wave's dq quarter
        float4 a[4], b[4];
        #pragma unroll
        for (int i = 0; i < 4; i++) {
          a[i] = *(const float4*)(As + (ty + 8 * i) * PAD + dq * 4);
          b[i] = *(const float4*)(Bs + (tx + 8 * i) * PAD + dq * 4);
        }
        #pragma unroll
        for (int i = 0; i < 4; i++)
          #pragma unroll
          for (int j = 0; j < 4; j++)
            acc[i][j] += a[i].x * b[j].x + a[i].y * b[j].y +
                         a[i].z * b[j].z + a[i].w * b[j].w;
      }
      __syncthreads();
    }

    // cross-wave reduction of partial dots into tileacc
    for (int ph = 0; ph < 4; ph++) {
      if (w == ph) {
        #pragma unroll
        for (int i = 0; i < 4; i++)
          #pragma unroll
          for (int j = 0; j < 4; j++) {
            int idx = (ty + 8 * i) * 37 + (tx + 8 * j);
            if (ph == 0) tileacc[idx] = acc[i][j];
            else tileacc[idx] += acc[i][j];
          }
      }
      __syncthreads();
    }

    // epilogue: 4 pairs per thread
    float inv0 = 1.f / bwArr[c];
    float contrib = 0.f;
    #pragma unroll
    for (int pi = 0; pi < 4; pi++) {
      int p = tid + (pi << 8);
      int j = p >> 5, k = p & 31;
      if (jbase + j < n && kbase + k < n) {
        float dot = tileacc[j * 37 + k];
        float d = fmaxf(sqc[off + jbase + j] + sqc[off + kbase + k] - 2.f * dot, 0.f);
        float s = inv0, kv = 0.f;
        #pragma unroll
        for (int q = 0; q < 5; q++) { kv += __expf(-d * s); s *= 0.5f; }
        contrib += sgnc[off + jbase + j] * sgnc[off + kbase + k] * kv;
      }
    }
    contrib *= wgt;
    for (int o = 32; o > 0; o >>= 1) contrib += __shfl_down(contrib, o, 64);
    if (lane == 0) red[w] = contrib;
    __syncthreads();
    if (tid == 0) atomicAdd(&losssum[c], red[0] + red[1] + red[2] + red[3]);
  }
}

// ---- K8: final scalar ----
__global__ __launch_bounds__(64) void k_final(
    const int* __restrict__ cnt, const int* __restrict__ srccnt,
    const int* __restrict__ tgtcnt, const float* __restrict__ losssum,
    float* out, int C) {
  int c = threadIdx.x;
  float loss = 0.f, cv = 0.f;
  if (c < C && srccnt[c] > 0 && tgtcnt[c] > 0) {
    float nf = (float)cnt[c];
    loss = losssum[c] / fmaxf(nf * nf, 1.f);
    cv = 1.f;
  }
  for (int o = 32; o > 0; o >>= 1) {
    loss += __shfl_down(loss, o, 64);
    cv   += __shfl_down(cv, o, 64);
  }
  if (threadIdx.x == 0) out[0] = loss / fmaxf(cv, 1.f);
}

extern "C" void kernel_launch(void* const* d_in, const int* in_sizes, int n_in,
                              void* d_out, int out_size, void* d_ws, size_t ws_size,
                              hipStream_t stream) {
  const float* source = (const float*)d_in[0];
  const float* target = (const float*)d_in[1];
  const int* slab     = (const int*)d_in[2];
  const float* tlabel = (const float*)d_in[3];
  const int* nsd_p    = (const int*)d_in[4];
  float* out = (float*)d_out;

  int S_total = in_sizes[2];
  int D = in_sizes[0] / S_total;   // 512
  int T = in_sizes[1] / D;         // 2048
  int C = in_sizes[3] / T;         // 31
  int NMAX = S_total + T;          // 6144 upper bound; actual N read on device

  // workspace layout (4-byte words); zeroed region first
  float* ws = (float*)d_ws;
  int* cnt      = (int*)ws;               // C
  int* srccnt   = cnt + C;                // C
  int* tgtcnt   = srccnt + C;             // C
  float* losssum = (float*)(tgtcnt + C);  // C
  float* ssum   = losssum + C;            // C
  float* colsum = ssum + C;               // C*D
  int zwords    = 5 * C + C * D;          // all zeroed

  int* offset   = (int*)(colsum + (size_t)C * D);  // C
  int* alloc    = offset + C;             // C
  int* misc     = alloc + C;              // 2
  float* bwArr  = (float*)(misc + 2);     // C
  int* lab      = (int*)(bwArr + C);      // NMAX
  float* sq     = (float*)(lab + NMAX);   // NMAX
  float* sqc    = sq + NMAX;              // NMAX
  float* sgnc   = sqc + NMAX;             // NMAX
  int* posArr   = (int*)(sgnc + NMAX);    // NMAX
  int* tileinfo = posArr + NMAX;          // TCAP
  int* tileinfo2 = tileinfo + TCAP;       // TCAP
  size_t words_used = (size_t)zwords + (3 * C + 2) + 5 * NMAX + 2 * TCAP;
  size_t cw = (words_used + 63) & ~(size_t)63;   // 256B-align compact
  float* compact = ws + cw;               // NMAX * D floats

  hipMemsetAsync(d_ws, 0, (size_t)zwords * sizeof(int), stream);

  k_prep<<<768, 256, 0, stream>>>(source, target, slab, tlabel, nsd_p,
                                  lab, sq, cnt, srccnt, tgtcnt, ssum,
                                  S_total, T, D, C);
  k_scan<<<1, 256, 0, stream>>>(cnt, offset, alloc, misc, tileinfo, tileinfo2, C);
  k_pos<<<(NMAX + 255) / 256, 256, 0, stream>>>(lab, sq, nsd_p, alloc,
                                                posArr, sqc, sgnc, S_total, T, C);
  k_gather<<<NMAX, 64, 0, stream>>>(source, target, nsd_p, posArr,
                                    compact, S_total, T, D);
  k_colsum<<<dim3(C, RCHUNK), 256, 0, stream>>>(compact, cnt, offset, colsum, D);
  k_bw<<<C, 256, 0, stream>>>(colsum, ssum, cnt, bwArr, D);
  k_pairs<<<512, 256, 0, stream>>>(compact, sqc, sgnc, tileinfo, tileinfo2,
                                   misc, bwArr, losssum, D);
  k_final<<<1, 64, 0, stream>>>(cnt, srccnt, tgtcnt, losssum, out, C);
}